// Round 14
// baseline (652.415 us; speedup 1.0000x reference)
//
#include <hip/hip_runtime.h>

#define N_NODES 50000
#define NBUCKET 196            // ceil(N/256) coarse dst-buckets
#define BCAP 6144              // bucket capacity (avg ~4082, +32 sigma)

// ---- phase 1: scatter packed (dst<<16|src) pairs into per-bucket regions ----
__global__ void scatter_pairs_kernel(const int* __restrict__ src, const int* __restrict__ dst,
                                     int E, int* __restrict__ bcur, unsigned* __restrict__ pairs) {
    int e = blockIdx.x * blockDim.x + threadIdx.x;
    if (e < E) {
        int d = dst[e];
        int b = d >> 8;
        int pos = atomicAdd(&bcur[b], 1);
        pairs[(size_t)b * BCAP + pos] = ((unsigned)d << 16) | (unsigned)src[e];
    }
}

// ---- tiny exclusive scan of the 196 bucket sizes ----
__global__ void bucket_scan_kernel(const int* __restrict__ bcur, int* __restrict__ bbase) {
    __shared__ int sh[256];
    int tid = threadIdx.x;
    int v = (tid < NBUCKET) ? bcur[tid] : 0;
    sh[tid] = v;
    __syncthreads();
    for (int off = 1; off < 256; off <<= 1) {
        int t = (tid >= off) ? sh[tid - off] : 0;
        __syncthreads();
        sh[tid] += t;
        __syncthreads();
    }
    if (tid < NBUCKET) bbase[tid] = sh[tid] - v;   // exclusive
}

// ---- phase 2: per-bucket counting sort -> col, rowptr, dis ----
__global__ __launch_bounds__(256) void bucket_build_kernel(
        const unsigned* __restrict__ pairs, const int* __restrict__ bcur,
        const int* __restrict__ bbase, int* __restrict__ col,
        int* __restrict__ rowptr, float* __restrict__ dis, int n) {
    __shared__ int cnt[256];
    __shared__ int cur[256];
    __shared__ int excl[256];
    const int b = blockIdx.x;
    const int tid = threadIdx.x;
    const int sz = bcur[b];
    const int base = bbase[b];
    const unsigned* bp = pairs + (size_t)b * BCAP;

    cnt[tid] = 0;
    __syncthreads();
    // histogram by low-8 dst bits (== global per-dst degree, since dst lives in 1 bucket)
    for (int i = tid; i < sz; i += 256)
        atomicAdd(&cnt[(bp[i] >> 16) & 255], 1);
    __syncthreads();
    int v = cnt[tid];
    excl[tid] = v;
    __syncthreads();
    for (int off = 1; off < 256; off <<= 1) {
        int t = (tid >= off) ? excl[tid - off] : 0;
        __syncthreads();
        excl[tid] += t;
        __syncthreads();
    }
    int ex = excl[tid] - v;                 // exclusive within bucket
    cur[tid] = base + ex;
    int idx = b * 256 + tid;
    if (idx <= n) rowptr[idx] = base + ex;  // last bucket's tid==n-49920 writes rowptr[n]=E
    if (idx < n) dis[idx] = rsqrtf((float)v + 1.0f);
    __syncthreads();
    // counting-sort scatter: col segment is contiguous per bucket
    for (int i = tid; i < sz; i += 256) {
        unsigned p = bp[i];
        int pos = atomicAdd(&cur[(p >> 16) & 255], 1);
        col[pos] = (int)(p & 0xFFFFu);
    }
}

// ---- float2 wave-level CSR aggregation (R13 proven) ----
__device__ __forceinline__ float2 agg_row_f2(const float* __restrict__ A,
        const int* __restrict__ rowptr, const int* __restrict__ col,
        int d, int eh, int f2, int lane) {
    const int beg = rowptr[d], deg = rowptr[d + 1] - beg;
    const float* __restrict__ Af = A + 2 * f2;
    float2 acc = make_float2(0.f, 0.f);
    for (int base = 0; base < deg; base += 64) {
        int idx = base + lane;
        int c = (idx < deg) ? col[beg + idx] : 0;
        int m = min(64, deg - base);
        int e = 0;
        for (; e + 16 <= m; e += 16) {
            int s0 = __shfl(c, e + 0 + eh),  s1 = __shfl(c, e + 2 + eh);
            int s2 = __shfl(c, e + 4 + eh),  s3 = __shfl(c, e + 6 + eh);
            int s4 = __shfl(c, e + 8 + eh),  s5 = __shfl(c, e + 10 + eh);
            int s6 = __shfl(c, e + 12 + eh), s7 = __shfl(c, e + 14 + eh);
            float2 v0 = *reinterpret_cast<const float2*>(&Af[(size_t)s0 * 64]);
            float2 v1 = *reinterpret_cast<const float2*>(&Af[(size_t)s1 * 64]);
            float2 v2 = *reinterpret_cast<const float2*>(&Af[(size_t)s2 * 64]);
            float2 v3 = *reinterpret_cast<const float2*>(&Af[(size_t)s3 * 64]);
            float2 v4 = *reinterpret_cast<const float2*>(&Af[(size_t)s4 * 64]);
            float2 v5 = *reinterpret_cast<const float2*>(&Af[(size_t)s5 * 64]);
            float2 v6 = *reinterpret_cast<const float2*>(&Af[(size_t)s6 * 64]);
            float2 v7 = *reinterpret_cast<const float2*>(&Af[(size_t)s7 * 64]);
            acc.x += ((v0.x + v1.x) + (v2.x + v3.x)) + ((v4.x + v5.x) + (v6.x + v7.x));
            acc.y += ((v0.y + v1.y) + (v2.y + v3.y)) + ((v4.y + v5.y) + (v6.y + v7.y));
        }
        for (; e + 2 <= m; e += 2) {
            int s = __shfl(c, e + eh);
            float2 v = *reinterpret_cast<const float2*>(&Af[(size_t)s * 64]);
            acc.x += v.x; acc.y += v.y;
        }
        if (e < m) {
            int s = __shfl(c, e);
            if (eh == 0) {
                float2 v = *reinterpret_cast<const float2*>(&Af[(size_t)s * 64]);
                acc.x += v.x; acc.y += v.y;
            }
        }
    }
    acc.x += __shfl_xor(acc.x, 32);
    acc.y += __shfl_xor(acc.y, 32);
    float2 sv = *reinterpret_cast<const float2*>(&Af[(size_t)d * 64]);
    acc.x += sv.x; acc.y += sv.y;
    return acc;
}

// ---- standalone register-blocked MM (layer 1): Y = dis[row] * (X[n,K] @ W[K,64]) ----
template<int K>
__global__ __launch_bounds__(256) void mm_tiled(const float* __restrict__ X,
        const float* __restrict__ W, const float* __restrict__ dis,
        float* __restrict__ Y, int n) {
    constexpr int KC = 64;
    __shared__ float xs[32][KC + 1];
    const int tid = threadIdx.x;
    const int j4 = tid & 15;
    const int rp = tid >> 4;
    const int row0 = blockIdx.x * 32;
    const int col0 = j4 * 4;
    float acc[2][4] = {};

    for (int kc = 0; kc < K; kc += KC) {
        __syncthreads();
        #pragma unroll
        for (int it = 0; it < 2; ++it) {
            int idx = it * 256 + tid;
            int r = idx >> 4, c4 = idx & 15;
            int row = row0 + r;
            float4 v = make_float4(0.f, 0.f, 0.f, 0.f);
            if (row < n) v = *reinterpret_cast<const float4*>(&X[(size_t)row * K + kc + c4 * 4]);
            xs[r][c4 * 4 + 0] = v.x; xs[r][c4 * 4 + 1] = v.y;
            xs[r][c4 * 4 + 2] = v.z; xs[r][c4 * 4 + 3] = v.w;
        }
        __syncthreads();
        #pragma unroll 16
        for (int k = 0; k < KC; ++k) {
            const float4 w = *reinterpret_cast<const float4*>(&W[(size_t)(kc + k) * 64 + col0]);
            const float x0 = xs[rp * 2 + 0][k];
            const float x1 = xs[rp * 2 + 1][k];
            acc[0][0] = fmaf(x0, w.x, acc[0][0]);
            acc[0][1] = fmaf(x0, w.y, acc[0][1]);
            acc[0][2] = fmaf(x0, w.z, acc[0][2]);
            acc[0][3] = fmaf(x0, w.w, acc[0][3]);
            acc[1][0] = fmaf(x1, w.x, acc[1][0]);
            acc[1][1] = fmaf(x1, w.y, acc[1][1]);
            acc[1][2] = fmaf(x1, w.z, acc[1][2]);
            acc[1][3] = fmaf(x1, w.w, acc[1][3]);
        }
    }
    #pragma unroll
    for (int r = 0; r < 2; ++r) {
        int row = row0 + rp * 2 + r;
        if (row < n) {
            float s = dis[row];
            *reinterpret_cast<float4*>(&Y[(size_t)row * 64 + col0]) =
                make_float4(acc[r][0] * s, acc[r][1] * s, acc[r][2] * s, acc[r][3] * s);
        }
    }
}

// ---- fused agg + MM, 32-row tile: xs = relu(dis*(agg+self)+b); Y = dis*(xs@W) ----
__global__ __launch_bounds__(256) void agg_mm_kernel(const float* __restrict__ A,
        const int* __restrict__ rowptr, const int* __restrict__ col,
        const float* __restrict__ dis, const float* __restrict__ bagg,
        const float* __restrict__ W, float* __restrict__ Y, int n) {
    __shared__ float xs[32][66];
    __shared__ float dl[32];
    const int tid = threadIdx.x;
    const int w = tid >> 6, lane = tid & 63;
    const int eh = lane >> 5, f2 = lane & 31;
    const int row0 = blockIdx.x * 32;
    const float2 bv = *reinterpret_cast<const float2*>(&bagg[2 * f2]);

    #pragma unroll
    for (int rr = 0; rr < 8; ++rr) {
        int lr = w * 8 + rr;
        int d = row0 + lr;
        if (d < n) {
            float2 acc = agg_row_f2(A, rowptr, col, d, eh, f2, lane);
            float dd = dis[d];
            if (eh == 0) {
                float2 o;
                o.x = fmaxf(dd * acc.x + bv.x, 0.0f);
                o.y = fmaxf(dd * acc.y + bv.y, 0.0f);
                *reinterpret_cast<float2*>(&xs[lr][2 * f2]) = o;
            }
            if (lane == 0) dl[lr] = dd;
        } else {
            if (eh == 0)
                *reinterpret_cast<float2*>(&xs[lr][2 * f2]) = make_float2(0.f, 0.f);
            if (lane == 0) dl[lr] = 0.0f;
        }
    }
    __syncthreads();

    const int j4 = tid & 15;
    const int rp = tid >> 4;
    const int col0 = j4 * 4;
    float acc[2][4] = {};
    #pragma unroll 16
    for (int k = 0; k < 64; ++k) {
        const float4 wv = *reinterpret_cast<const float4*>(&W[(size_t)k * 64 + col0]);
        const float x0 = xs[rp * 2 + 0][k];
        const float x1 = xs[rp * 2 + 1][k];
        acc[0][0] = fmaf(x0, wv.x, acc[0][0]);
        acc[0][1] = fmaf(x0, wv.y, acc[0][1]);
        acc[0][2] = fmaf(x0, wv.z, acc[0][2]);
        acc[0][3] = fmaf(x0, wv.w, acc[0][3]);
        acc[1][0] = fmaf(x1, wv.x, acc[1][0]);
        acc[1][1] = fmaf(x1, wv.y, acc[1][1]);
        acc[1][2] = fmaf(x1, wv.z, acc[1][2]);
        acc[1][3] = fmaf(x1, wv.w, acc[1][3]);
    }
    #pragma unroll
    for (int r = 0; r < 2; ++r) {
        int row = row0 + rp * 2 + r;
        if (row < n) {
            float s = dl[rp * 2 + r];
            *reinterpret_cast<float4*>(&Y[(size_t)row * 64 + col0]) =
                make_float4(acc[r][0] * s, acc[r][1] * s, acc[r][2] * s, acc[r][3] * s);
        }
    }
}

// ---- fused agg + FFN head, 32-row tile ----
__global__ __launch_bounds__(256) void agg_ffn_kernel(const float* __restrict__ A,
        const int* __restrict__ rowptr, const int* __restrict__ col,
        const float* __restrict__ dis, const float* __restrict__ bagg,
        const float* __restrict__ Wf1, const float* __restrict__ bf1,
        const float* __restrict__ Wf2, const float* __restrict__ bf2,
        float* __restrict__ out, int n) {
    __shared__ float xs[32][66];
    __shared__ float h1[32][65];
    const int tid = threadIdx.x;
    const int w = tid >> 6, lane = tid & 63;
    const int eh = lane >> 5, f2 = lane & 31;
    const int row0 = blockIdx.x * 32;
    const float2 bv = *reinterpret_cast<const float2*>(&bagg[2 * f2]);

    #pragma unroll
    for (int rr = 0; rr < 8; ++rr) {
        int lr = w * 8 + rr;
        int d = row0 + lr;
        if (d < n) {
            float2 acc = agg_row_f2(A, rowptr, col, d, eh, f2, lane);
            float dd = dis[d];
            if (eh == 0) {
                float2 o;
                o.x = fmaxf(dd * acc.x + bv.x, 0.0f);
                o.y = fmaxf(dd * acc.y + bv.y, 0.0f);
                *reinterpret_cast<float2*>(&xs[lr][2 * f2]) = o;
            }
        } else {
            if (eh == 0)
                *reinterpret_cast<float2*>(&xs[lr][2 * f2]) = make_float2(0.f, 0.f);
        }
    }
    __syncthreads();

    const int j4 = tid & 15;
    const int rp = tid >> 4;
    const int col0 = j4 * 4;
    float acc[2][4] = {};
    #pragma unroll 16
    for (int k = 0; k < 64; ++k) {
        const float4 wv = *reinterpret_cast<const float4*>(&Wf1[(size_t)k * 64 + col0]);
        const float x0 = xs[rp * 2 + 0][k];
        const float x1 = xs[rp * 2 + 1][k];
        acc[0][0] = fmaf(x0, wv.x, acc[0][0]);
        acc[0][1] = fmaf(x0, wv.y, acc[0][1]);
        acc[0][2] = fmaf(x0, wv.z, acc[0][2]);
        acc[0][3] = fmaf(x0, wv.w, acc[0][3]);
        acc[1][0] = fmaf(x1, wv.x, acc[1][0]);
        acc[1][1] = fmaf(x1, wv.y, acc[1][1]);
        acc[1][2] = fmaf(x1, wv.z, acc[1][2]);
        acc[1][3] = fmaf(x1, wv.w, acc[1][3]);
    }
    #pragma unroll
    for (int c = 0; c < 4; ++c) {
        float b = bf1[col0 + c];
        h1[rp * 2 + 0][col0 + c] = fmaxf(acc[0][c] + b, 0.0f);
        h1[rp * 2 + 1][col0 + c] = fmaxf(acc[1][c] + b, 0.0f);
    }
    __syncthreads();

    const int lr = tid >> 3;
    const int cg = tid & 7;
    if (cg < 5) {
        float a0 = bf2[cg * 2 + 0], a1 = bf2[cg * 2 + 1];
        #pragma unroll 16
        for (int k = 0; k < 64; ++k) {
            float xv = h1[lr][k];
            a0 = fmaf(xv, Wf2[(size_t)k * 10 + cg * 2 + 0], a0);
            a1 = fmaf(xv, Wf2[(size_t)k * 10 + cg * 2 + 1], a1);
        }
        int row = row0 + lr;
        if (row < n) {
            out[(size_t)row * 10 + cg * 2 + 0] = a0;
            out[(size_t)row * 10 + cg * 2 + 1] = a1;
        }
    }
}

extern "C" void kernel_launch(void* const* d_in, const int* in_sizes, int n_in,
                              void* d_out, int out_size, void* d_ws, size_t ws_size,
                              hipStream_t stream) {
    const float* x   = (const float*)d_in[0];
    const int*   ei  = (const int*)d_in[1];
    const float* W1  = (const float*)d_in[2];
    const float* b1  = (const float*)d_in[3];
    const float* W2  = (const float*)d_in[4];
    const float* b2  = (const float*)d_in[5];
    const float* W3  = (const float*)d_in[6];
    const float* b3  = (const float*)d_in[7];
    const float* Wf1 = (const float*)d_in[8];
    const float* bf1 = (const float*)d_in[9];
    const float* Wf2 = (const float*)d_in[10];
    const float* bf2 = (const float*)d_in[11];
    float* out = (float*)d_out;

    const int N = N_NODES;
    const int E = in_sizes[1] / 2;
    const int* src = ei;
    const int* dst = ei + E;

    // workspace layout
    char* p = (char*)d_ws;
    int*   bcur   = (int*)p;                 p += (size_t)256 * 4;
    int*   bbase  = (int*)p;                 p += (size_t)256 * 4;
    int*   rowptr = (int*)p;                 p += (size_t)(50176 + 64) * 4;
    float* dis    = (float*)p;               p += (size_t)50176 * 4;
    int*   col    = (int*)p;                 p += (size_t)E * 4;
    float* A1     = (float*)p;               p += (size_t)N * 64 * 4;
    float* A2     = (float*)p;
    unsigned* pairs = (unsigned*)A2;         // pairs buffer aliases A2 (dead before 1st agg_mm)

    // ---- CSR build via bucket counting sort ----
    hipMemsetAsync(bcur, 0, NBUCKET * sizeof(int), stream);
    scatter_pairs_kernel<<<(E + 255) / 256, 256, 0, stream>>>(src, dst, E, bcur, pairs);
    bucket_scan_kernel<<<1, 256, 0, stream>>>(bcur, bbase);
    bucket_build_kernel<<<NBUCKET, 256, 0, stream>>>(pairs, bcur, bbase, col, rowptr, dis, N);

    const int grid32 = (N + 31) / 32;      // 1563 blocks

    // A1 = dis * (x @ W1)
    mm_tiled<128><<<grid32, 256, 0, stream>>>(x, W1, dis, A1, N);
    // A2 = dis * (relu(dis*(agg(A1)+self)+b1) @ W2)   [pairs dead from here]
    agg_mm_kernel<<<grid32, 256, 0, stream>>>(A1, rowptr, col, dis, b1, W2, A2, N);
    // A1 = dis * (relu(dis*(agg(A2)+self)+b2) @ W3)
    agg_mm_kernel<<<grid32, 256, 0, stream>>>(A2, rowptr, col, dis, b2, W3, A1, N);
    // out = ffn(relu(dis*(agg(A1)+self)+b3))
    agg_ffn_kernel<<<grid32, 256, 0, stream>>>(A1, rowptr, col, dis, b3,
                                               Wf1, bf1, Wf2, bf2, out, N);
}

// Round 15
// 225.912 us; speedup vs baseline: 2.8879x; 2.8879x over previous
//
#include <hip/hip_runtime.h>

#define N_NODES 50000
#define NBUCKET 196            // ceil(N/256) coarse dst-buckets (dst>>8)
#define EPB 1024               // edges per histogram/scatter block

// ---- build pass 1: per-block LDS histogram of dst>>8 (no global atomics) ----
__global__ __launch_bounds__(256) void hist_kernel(const int* __restrict__ dst, int E,
                                                   int* __restrict__ hist, int nblkE) {
    __shared__ int cnt[NBUCKET];
    const int tid = threadIdx.x;
    for (int b = tid; b < NBUCKET; b += 256) cnt[b] = 0;
    __syncthreads();
    const int e0 = blockIdx.x * EPB;
    for (int i = tid; i < EPB; i += 256) {
        int e = e0 + i;
        if (e < E) atomicAdd(&cnt[dst[e] >> 8], 1);   // LDS atomic, ~5/counter
    }
    __syncthreads();
    for (int b = tid; b < NBUCKET; b += 256)
        hist[(size_t)b * nblkE + blockIdx.x] = cnt[b];
}

// ---- build pass 2: per-bucket exclusive scan over blocks (in place) + totals ----
__global__ __launch_bounds__(256) void colscan_kernel(int* __restrict__ hist, int nblkE,
                                                      int* __restrict__ btot) {
    __shared__ int sh[256];
    const int b = blockIdx.x, tid = threadIdx.x;
    int* h = hist + (size_t)b * nblkE;
    const int C = (nblkE + 255) / 256;
    const int lo = tid * C, hi = min(lo + C, nblkE);
    int s = 0;
    for (int i = lo; i < hi; ++i) s += h[i];
    sh[tid] = s;
    __syncthreads();
    for (int off = 1; off < 256; off <<= 1) {
        int t = (tid >= off) ? sh[tid - off] : 0;
        __syncthreads();
        sh[tid] += t;
        __syncthreads();
    }
    int run = (tid > 0) ? sh[tid - 1] : 0;
    for (int i = lo; i < hi; ++i) { int v = h[i]; h[i] = run; run += v; }
    if (tid == 255) btot[b] = sh[255];
}

// ---- build pass 3: exclusive scan of 196 bucket totals ----
__global__ void btot_scan_kernel(const int* __restrict__ btot, int* __restrict__ bbase) {
    __shared__ int sh[256];
    int tid = threadIdx.x;
    int v = (tid < NBUCKET) ? btot[tid] : 0;
    sh[tid] = v;
    __syncthreads();
    for (int off = 1; off < 256; off <<= 1) {
        int t = (tid >= off) ? sh[tid - off] : 0;
        __syncthreads();
        sh[tid] += t;
        __syncthreads();
    }
    if (tid < NBUCKET) bbase[tid] = sh[tid] - v;   // exclusive
}

// ---- build pass 4: scatter packed (dst<<16|src) pairs, LDS cursors only ----
__global__ __launch_bounds__(256) void scatter_kernel(const int* __restrict__ src,
        const int* __restrict__ dst, int E, const int* __restrict__ hist,
        const int* __restrict__ bbase, int nblkE, unsigned* __restrict__ pairs) {
    __shared__ int cur[NBUCKET];
    const int tid = threadIdx.x;
    for (int b = tid; b < NBUCKET; b += 256)
        cur[b] = bbase[b] + hist[(size_t)b * nblkE + blockIdx.x];
    __syncthreads();
    const int e0 = blockIdx.x * EPB;
    for (int i = tid; i < EPB; i += 256) {
        int e = e0 + i;
        if (e < E) {
            int d = dst[e];
            int pos = atomicAdd(&cur[d >> 8], 1);   // LDS atomic
            pairs[pos] = ((unsigned)d << 16) | (unsigned)src[e];
        }
    }
}

// ---- build pass 5: per-bucket counting sort -> col, rowptr, dis (R14-proven logic) ----
__global__ __launch_bounds__(256) void bucket_build_kernel(
        const unsigned* __restrict__ pairs, const int* __restrict__ btot,
        const int* __restrict__ bbase, int* __restrict__ col,
        int* __restrict__ rowptr, float* __restrict__ dis, int n) {
    __shared__ int cnt[256];
    __shared__ int cur[256];
    __shared__ int excl[256];
    const int b = blockIdx.x;
    const int tid = threadIdx.x;
    const int sz = btot[b];
    const int base = bbase[b];
    const unsigned* bp = pairs + base;

    cnt[tid] = 0;
    __syncthreads();
    for (int i = tid; i < sz; i += 256)
        atomicAdd(&cnt[(bp[i] >> 16) & 255], 1);
    __syncthreads();
    int v = cnt[tid];
    excl[tid] = v;
    __syncthreads();
    for (int off = 1; off < 256; off <<= 1) {
        int t = (tid >= off) ? excl[tid - off] : 0;
        __syncthreads();
        excl[tid] += t;
        __syncthreads();
    }
    int ex = excl[tid] - v;
    cur[tid] = base + ex;
    int idx = b * 256 + tid;
    if (idx <= n) rowptr[idx] = base + ex;
    if (idx < n) dis[idx] = rsqrtf((float)v + 1.0f);
    __syncthreads();
    for (int i = tid; i < sz; i += 256) {
        unsigned p = bp[i];
        int pos = atomicAdd(&cur[(p >> 16) & 255], 1);
        col[pos] = (int)(p & 0xFFFFu);
    }
}

// ---- float2 wave-level CSR aggregation (R13 proven) ----
__device__ __forceinline__ float2 agg_row_f2(const float* __restrict__ A,
        const int* __restrict__ rowptr, const int* __restrict__ col,
        int d, int eh, int f2, int lane) {
    const int beg = rowptr[d], deg = rowptr[d + 1] - beg;
    const float* __restrict__ Af = A + 2 * f2;
    float2 acc = make_float2(0.f, 0.f);
    for (int base = 0; base < deg; base += 64) {
        int idx = base + lane;
        int c = (idx < deg) ? col[beg + idx] : 0;
        int m = min(64, deg - base);
        int e = 0;
        for (; e + 16 <= m; e += 16) {
            int s0 = __shfl(c, e + 0 + eh),  s1 = __shfl(c, e + 2 + eh);
            int s2 = __shfl(c, e + 4 + eh),  s3 = __shfl(c, e + 6 + eh);
            int s4 = __shfl(c, e + 8 + eh),  s5 = __shfl(c, e + 10 + eh);
            int s6 = __shfl(c, e + 12 + eh), s7 = __shfl(c, e + 14 + eh);
            float2 v0 = *reinterpret_cast<const float2*>(&Af[(size_t)s0 * 64]);
            float2 v1 = *reinterpret_cast<const float2*>(&Af[(size_t)s1 * 64]);
            float2 v2 = *reinterpret_cast<const float2*>(&Af[(size_t)s2 * 64]);
            float2 v3 = *reinterpret_cast<const float2*>(&Af[(size_t)s3 * 64]);
            float2 v4 = *reinterpret_cast<const float2*>(&Af[(size_t)s4 * 64]);
            float2 v5 = *reinterpret_cast<const float2*>(&Af[(size_t)s5 * 64]);
            float2 v6 = *reinterpret_cast<const float2*>(&Af[(size_t)s6 * 64]);
            float2 v7 = *reinterpret_cast<const float2*>(&Af[(size_t)s7 * 64]);
            acc.x += ((v0.x + v1.x) + (v2.x + v3.x)) + ((v4.x + v5.x) + (v6.x + v7.x));
            acc.y += ((v0.y + v1.y) + (v2.y + v3.y)) + ((v4.y + v5.y) + (v6.y + v7.y));
        }
        for (; e + 2 <= m; e += 2) {
            int s = __shfl(c, e + eh);
            float2 v = *reinterpret_cast<const float2*>(&Af[(size_t)s * 64]);
            acc.x += v.x; acc.y += v.y;
        }
        if (e < m) {
            int s = __shfl(c, e);
            if (eh == 0) {
                float2 v = *reinterpret_cast<const float2*>(&Af[(size_t)s * 64]);
                acc.x += v.x; acc.y += v.y;
            }
        }
    }
    acc.x += __shfl_xor(acc.x, 32);
    acc.y += __shfl_xor(acc.y, 32);
    float2 sv = *reinterpret_cast<const float2*>(&Af[(size_t)d * 64]);
    acc.x += sv.x; acc.y += sv.y;
    return acc;
}

// ---- standalone register-blocked MM (layer 1): Y = dis[row] * (X[n,K] @ W[K,64]) ----
template<int K>
__global__ __launch_bounds__(256) void mm_tiled(const float* __restrict__ X,
        const float* __restrict__ W, const float* __restrict__ dis,
        float* __restrict__ Y, int n) {
    constexpr int KC = 64;
    __shared__ float xs[32][KC + 1];
    const int tid = threadIdx.x;
    const int j4 = tid & 15;
    const int rp = tid >> 4;
    const int row0 = blockIdx.x * 32;
    const int col0 = j4 * 4;
    float acc[2][4] = {};

    for (int kc = 0; kc < K; kc += KC) {
        __syncthreads();
        #pragma unroll
        for (int it = 0; it < 2; ++it) {
            int idx = it * 256 + tid;
            int r = idx >> 4, c4 = idx & 15;
            int row = row0 + r;
            float4 v = make_float4(0.f, 0.f, 0.f, 0.f);
            if (row < n) v = *reinterpret_cast<const float4*>(&X[(size_t)row * K + kc + c4 * 4]);
            xs[r][c4 * 4 + 0] = v.x; xs[r][c4 * 4 + 1] = v.y;
            xs[r][c4 * 4 + 2] = v.z; xs[r][c4 * 4 + 3] = v.w;
        }
        __syncthreads();
        #pragma unroll 16
        for (int k = 0; k < KC; ++k) {
            const float4 w = *reinterpret_cast<const float4*>(&W[(size_t)(kc + k) * 64 + col0]);
            const float x0 = xs[rp * 2 + 0][k];
            const float x1 = xs[rp * 2 + 1][k];
            acc[0][0] = fmaf(x0, w.x, acc[0][0]);
            acc[0][1] = fmaf(x0, w.y, acc[0][1]);
            acc[0][2] = fmaf(x0, w.z, acc[0][2]);
            acc[0][3] = fmaf(x0, w.w, acc[0][3]);
            acc[1][0] = fmaf(x1, w.x, acc[1][0]);
            acc[1][1] = fmaf(x1, w.y, acc[1][1]);
            acc[1][2] = fmaf(x1, w.z, acc[1][2]);
            acc[1][3] = fmaf(x1, w.w, acc[1][3]);
        }
    }
    #pragma unroll
    for (int r = 0; r < 2; ++r) {
        int row = row0 + rp * 2 + r;
        if (row < n) {
            float s = dis[row];
            *reinterpret_cast<float4*>(&Y[(size_t)row * 64 + col0]) =
                make_float4(acc[r][0] * s, acc[r][1] * s, acc[r][2] * s, acc[r][3] * s);
        }
    }
}

// ---- fused agg + MM, 32-row tile: xs = relu(dis*(agg+self)+b); Y = dis*(xs@W) ----
__global__ __launch_bounds__(256) void agg_mm_kernel(const float* __restrict__ A,
        const int* __restrict__ rowptr, const int* __restrict__ col,
        const float* __restrict__ dis, const float* __restrict__ bagg,
        const float* __restrict__ W, float* __restrict__ Y, int n) {
    __shared__ float xs[32][66];
    __shared__ float dl[32];
    const int tid = threadIdx.x;
    const int w = tid >> 6, lane = tid & 63;
    const int eh = lane >> 5, f2 = lane & 31;
    const int row0 = blockIdx.x * 32;
    const float2 bv = *reinterpret_cast<const float2*>(&bagg[2 * f2]);

    #pragma unroll
    for (int rr = 0; rr < 8; ++rr) {
        int lr = w * 8 + rr;
        int d = row0 + lr;
        if (d < n) {
            float2 acc = agg_row_f2(A, rowptr, col, d, eh, f2, lane);
            float dd = dis[d];
            if (eh == 0) {
                float2 o;
                o.x = fmaxf(dd * acc.x + bv.x, 0.0f);
                o.y = fmaxf(dd * acc.y + bv.y, 0.0f);
                *reinterpret_cast<float2*>(&xs[lr][2 * f2]) = o;
            }
            if (lane == 0) dl[lr] = dd;
        } else {
            if (eh == 0)
                *reinterpret_cast<float2*>(&xs[lr][2 * f2]) = make_float2(0.f, 0.f);
            if (lane == 0) dl[lr] = 0.0f;
        }
    }
    __syncthreads();

    const int j4 = tid & 15;
    const int rp = tid >> 4;
    const int col0 = j4 * 4;
    float acc[2][4] = {};
    #pragma unroll 16
    for (int k = 0; k < 64; ++k) {
        const float4 wv = *reinterpret_cast<const float4*>(&W[(size_t)k * 64 + col0]);
        const float x0 = xs[rp * 2 + 0][k];
        const float x1 = xs[rp * 2 + 1][k];
        acc[0][0] = fmaf(x0, wv.x, acc[0][0]);
        acc[0][1] = fmaf(x0, wv.y, acc[0][1]);
        acc[0][2] = fmaf(x0, wv.z, acc[0][2]);
        acc[0][3] = fmaf(x0, wv.w, acc[0][3]);
        acc[1][0] = fmaf(x1, wv.x, acc[1][0]);
        acc[1][1] = fmaf(x1, wv.y, acc[1][1]);
        acc[1][2] = fmaf(x1, wv.z, acc[1][2]);
        acc[1][3] = fmaf(x1, wv.w, acc[1][3]);
    }
    #pragma unroll
    for (int r = 0; r < 2; ++r) {
        int row = row0 + rp * 2 + r;
        if (row < n) {
            float s = dl[rp * 2 + r];
            *reinterpret_cast<float4*>(&Y[(size_t)row * 64 + col0]) =
                make_float4(acc[r][0] * s, acc[r][1] * s, acc[r][2] * s, acc[r][3] * s);
        }
    }
}

// ---- fused agg + FFN head, 32-row tile ----
__global__ __launch_bounds__(256) void agg_ffn_kernel(const float* __restrict__ A,
        const int* __restrict__ rowptr, const int* __restrict__ col,
        const float* __restrict__ dis, const float* __restrict__ bagg,
        const float* __restrict__ Wf1, const float* __restrict__ bf1,
        const float* __restrict__ Wf2, const float* __restrict__ bf2,
        float* __restrict__ out, int n) {
    __shared__ float xs[32][66];
    __shared__ float h1[32][65];
    const int tid = threadIdx.x;
    const int w = tid >> 6, lane = tid & 63;
    const int eh = lane >> 5, f2 = lane & 31;
    const int row0 = blockIdx.x * 32;
    const float2 bv = *reinterpret_cast<const float2*>(&bagg[2 * f2]);

    #pragma unroll
    for (int rr = 0; rr < 8; ++rr) {
        int lr = w * 8 + rr;
        int d = row0 + lr;
        if (d < n) {
            float2 acc = agg_row_f2(A, rowptr, col, d, eh, f2, lane);
            float dd = dis[d];
            if (eh == 0) {
                float2 o;
                o.x = fmaxf(dd * acc.x + bv.x, 0.0f);
                o.y = fmaxf(dd * acc.y + bv.y, 0.0f);
                *reinterpret_cast<float2*>(&xs[lr][2 * f2]) = o;
            }
        } else {
            if (eh == 0)
                *reinterpret_cast<float2*>(&xs[lr][2 * f2]) = make_float2(0.f, 0.f);
        }
    }
    __syncthreads();

    const int j4 = tid & 15;
    const int rp = tid >> 4;
    const int col0 = j4 * 4;
    float acc[2][4] = {};
    #pragma unroll 16
    for (int k = 0; k < 64; ++k) {
        const float4 wv = *reinterpret_cast<const float4*>(&Wf1[(size_t)k * 64 + col0]);
        const float x0 = xs[rp * 2 + 0][k];
        const float x1 = xs[rp * 2 + 1][k];
        acc[0][0] = fmaf(x0, wv.x, acc[0][0]);
        acc[0][1] = fmaf(x0, wv.y, acc[0][1]);
        acc[0][2] = fmaf(x0, wv.z, acc[0][2]);
        acc[0][3] = fmaf(x0, wv.w, acc[0][3]);
        acc[1][0] = fmaf(x1, wv.x, acc[1][0]);
        acc[1][1] = fmaf(x1, wv.y, acc[1][1]);
        acc[1][2] = fmaf(x1, wv.z, acc[1][2]);
        acc[1][3] = fmaf(x1, wv.w, acc[1][3]);
    }
    #pragma unroll
    for (int c = 0; c < 4; ++c) {
        float b = bf1[col0 + c];
        h1[rp * 2 + 0][col0 + c] = fmaxf(acc[0][c] + b, 0.0f);
        h1[rp * 2 + 1][col0 + c] = fmaxf(acc[1][c] + b, 0.0f);
    }
    __syncthreads();

    const int lr = tid >> 3;
    const int cg = tid & 7;
    if (cg < 5) {
        float a0 = bf2[cg * 2 + 0], a1 = bf2[cg * 2 + 1];
        #pragma unroll 16
        for (int k = 0; k < 64; ++k) {
            float xv = h1[lr][k];
            a0 = fmaf(xv, Wf2[(size_t)k * 10 + cg * 2 + 0], a0);
            a1 = fmaf(xv, Wf2[(size_t)k * 10 + cg * 2 + 1], a1);
        }
        int row = row0 + lr;
        if (row < n) {
            out[(size_t)row * 10 + cg * 2 + 0] = a0;
            out[(size_t)row * 10 + cg * 2 + 1] = a1;
        }
    }
}

extern "C" void kernel_launch(void* const* d_in, const int* in_sizes, int n_in,
                              void* d_out, int out_size, void* d_ws, size_t ws_size,
                              hipStream_t stream) {
    const float* x   = (const float*)d_in[0];
    const int*   ei  = (const int*)d_in[1];
    const float* W1  = (const float*)d_in[2];
    const float* b1  = (const float*)d_in[3];
    const float* W2  = (const float*)d_in[4];
    const float* b2  = (const float*)d_in[5];
    const float* W3  = (const float*)d_in[6];
    const float* b3  = (const float*)d_in[7];
    const float* Wf1 = (const float*)d_in[8];
    const float* bf1 = (const float*)d_in[9];
    const float* Wf2 = (const float*)d_in[10];
    const float* bf2 = (const float*)d_in[11];
    float* out = (float*)d_out;

    const int N = N_NODES;
    const int E = in_sizes[1] / 2;
    const int* src = ei;
    const int* dst = ei + E;
    const int nblkE = (E + EPB - 1) / EPB;   // 782

    // workspace layout
    char* p = (char*)d_ws;
    int*   btot   = (int*)p;                 p += (size_t)256 * 4;
    int*   bbase  = (int*)p;                 p += (size_t)256 * 4;
    int*   rowptr = (int*)p;                 p += (size_t)(50176 + 64) * 4;
    float* dis    = (float*)p;               p += (size_t)50176 * 4;
    int*   col    = (int*)p;                 p += (size_t)E * 4;
    int*   hist   = (int*)p;                 p += (size_t)NBUCKET * nblkE * 4;
    float* A1     = (float*)p;               p += (size_t)N * 64 * 4;
    float* A2     = (float*)p;
    unsigned* pairs = (unsigned*)A2;         // aliases A2 (dead before 1st agg_mm)

    // ---- CSR build: deterministic bucket counting sort (no global atomics) ----
    hist_kernel<<<nblkE, 256, 0, stream>>>(dst, E, hist, nblkE);
    colscan_kernel<<<NBUCKET, 256, 0, stream>>>(hist, nblkE, btot);
    btot_scan_kernel<<<1, 256, 0, stream>>>(btot, bbase);
    scatter_kernel<<<nblkE, 256, 0, stream>>>(src, dst, E, hist, bbase, nblkE, pairs);
    bucket_build_kernel<<<NBUCKET, 256, 0, stream>>>(pairs, btot, bbase, col, rowptr, dis, N);

    const int grid32 = (N + 31) / 32;      // 1563 blocks

    // A1 = dis * (x @ W1)
    mm_tiled<128><<<grid32, 256, 0, stream>>>(x, W1, dis, A1, N);
    // A2 = dis * (relu(dis*(agg(A1)+self)+b1) @ W2)   [pairs dead from here]
    agg_mm_kernel<<<grid32, 256, 0, stream>>>(A1, rowptr, col, dis, b1, W2, A2, N);
    // A1 = dis * (relu(dis*(agg(A2)+self)+b2) @ W3)
    agg_mm_kernel<<<grid32, 256, 0, stream>>>(A2, rowptr, col, dis, b2, W3, A1, N);
    // out = ffn(relu(dis*(agg(A1)+self)+b3))
    agg_ffn_kernel<<<grid32, 256, 0, stream>>>(A1, rowptr, col, dis, b3,
                                               Wf1, bf1, Wf2, bf2, out, N);
}

// Round 16
// 199.732 us; speedup vs baseline: 3.2664x; 1.1311x over previous
//
#include <hip/hip_runtime.h>
#include <hip/hip_fp16.h>

#define N_NODES 50000
#define NBUCKET 196            // ceil(N/256) coarse dst-buckets (dst>>8)
#define EPB 1024               // edges per histogram/scatter block

// ---- build pass 1: per-block LDS histogram of dst>>8 (no global atomics) ----
__global__ __launch_bounds__(256) void hist_kernel(const int* __restrict__ dst, int E,
                                                   int* __restrict__ hist, int nblkE) {
    __shared__ int cnt[NBUCKET];
    const int tid = threadIdx.x;
    for (int b = tid; b < NBUCKET; b += 256) cnt[b] = 0;
    __syncthreads();
    const int e0 = blockIdx.x * EPB;
    for (int i = tid; i < EPB; i += 256) {
        int e = e0 + i;
        if (e < E) atomicAdd(&cnt[dst[e] >> 8], 1);
    }
    __syncthreads();
    for (int b = tid; b < NBUCKET; b += 256)
        hist[(size_t)b * nblkE + blockIdx.x] = cnt[b];
}

// ---- build pass 2: per-bucket exclusive scan over blocks (in place) + totals ----
__global__ __launch_bounds__(256) void colscan_kernel(int* __restrict__ hist, int nblkE,
                                                      int* __restrict__ btot) {
    __shared__ int sh[256];
    const int b = blockIdx.x, tid = threadIdx.x;
    int* h = hist + (size_t)b * nblkE;
    const int C = (nblkE + 255) / 256;
    const int lo = tid * C, hi = min(lo + C, nblkE);
    int s = 0;
    for (int i = lo; i < hi; ++i) s += h[i];
    sh[tid] = s;
    __syncthreads();
    for (int off = 1; off < 256; off <<= 1) {
        int t = (tid >= off) ? sh[tid - off] : 0;
        __syncthreads();
        sh[tid] += t;
        __syncthreads();
    }
    int run = (tid > 0) ? sh[tid - 1] : 0;
    for (int i = lo; i < hi; ++i) { int v = h[i]; h[i] = run; run += v; }
    if (tid == 255) btot[b] = sh[255];
}

// ---- build pass 3: exclusive scan of 196 bucket totals ----
__global__ void btot_scan_kernel(const int* __restrict__ btot, int* __restrict__ bbase) {
    __shared__ int sh[256];
    int tid = threadIdx.x;
    int v = (tid < NBUCKET) ? btot[tid] : 0;
    sh[tid] = v;
    __syncthreads();
    for (int off = 1; off < 256; off <<= 1) {
        int t = (tid >= off) ? sh[tid - off] : 0;
        __syncthreads();
        sh[tid] += t;
        __syncthreads();
    }
    if (tid < NBUCKET) bbase[tid] = sh[tid] - v;   // exclusive
}

// ---- build pass 4: scatter packed (dst<<16|src) pairs, LDS cursors only ----
__global__ __launch_bounds__(256) void scatter_kernel(const int* __restrict__ src,
        const int* __restrict__ dst, int E, const int* __restrict__ hist,
        const int* __restrict__ bbase, int nblkE, unsigned* __restrict__ pairs) {
    __shared__ int cur[NBUCKET];
    const int tid = threadIdx.x;
    for (int b = tid; b < NBUCKET; b += 256)
        cur[b] = bbase[b] + hist[(size_t)b * nblkE + blockIdx.x];
    __syncthreads();
    const int e0 = blockIdx.x * EPB;
    for (int i = tid; i < EPB; i += 256) {
        int e = e0 + i;
        if (e < E) {
            int d = dst[e];
            int pos = atomicAdd(&cur[d >> 8], 1);   // LDS atomic
            pairs[pos] = ((unsigned)d << 16) | (unsigned)src[e];
        }
    }
}

// ---- build pass 5: per-bucket counting sort -> col, rowptr, dis ----
__global__ __launch_bounds__(256) void bucket_build_kernel(
        const unsigned* __restrict__ pairs, const int* __restrict__ btot,
        const int* __restrict__ bbase, int* __restrict__ col,
        int* __restrict__ rowptr, float* __restrict__ dis, int n) {
    __shared__ int cnt[256];
    __shared__ int cur[256];
    __shared__ int excl[256];
    const int b = blockIdx.x;
    const int tid = threadIdx.x;
    const int sz = btot[b];
    const int base = bbase[b];
    const unsigned* bp = pairs + base;

    cnt[tid] = 0;
    __syncthreads();
    for (int i = tid; i < sz; i += 256)
        atomicAdd(&cnt[(bp[i] >> 16) & 255], 1);
    __syncthreads();
    int v = cnt[tid];
    excl[tid] = v;
    __syncthreads();
    for (int off = 1; off < 256; off <<= 1) {
        int t = (tid >= off) ? excl[tid - off] : 0;
        __syncthreads();
        excl[tid] += t;
        __syncthreads();
    }
    int ex = excl[tid] - v;
    cur[tid] = base + ex;
    int idx = b * 256 + tid;
    if (idx <= n) rowptr[idx] = base + ex;
    if (idx < n) dis[idx] = rsqrtf((float)v + 1.0f);
    __syncthreads();
    for (int i = tid; i < sz; i += 256) {
        unsigned p = bp[i];
        int pos = atomicAdd(&cur[(p >> 16) & 255], 1);
        col[pos] = (int)(p & 0xFFFFu);
    }
}

// ---- fp16 wave-level CSR aggregation (fp32 accumulate) ----
// eh = lane>>5 picks one of 2 edge streams; f2 = lane&31 covers features 2f2,2f2+1
// via one half2 (4B) load. Row = 128B = 2 cache lines.
__device__ __forceinline__ float2 agg_row_h2(const __half* __restrict__ A,
        const int* __restrict__ rowptr, const int* __restrict__ col,
        int d, int eh, int f2, int lane) {
    const int beg = rowptr[d], deg = rowptr[d + 1] - beg;
    const __half* __restrict__ Af = A + 2 * f2;
    float2 acc = make_float2(0.f, 0.f);
    for (int base = 0; base < deg; base += 64) {
        int idx = base + lane;
        int c = (idx < deg) ? col[beg + idx] : 0;
        int m = min(64, deg - base);
        int e = 0;
        for (; e + 16 <= m; e += 16) {
            int s0 = __shfl(c, e + 0 + eh),  s1 = __shfl(c, e + 2 + eh);
            int s2 = __shfl(c, e + 4 + eh),  s3 = __shfl(c, e + 6 + eh);
            int s4 = __shfl(c, e + 8 + eh),  s5 = __shfl(c, e + 10 + eh);
            int s6 = __shfl(c, e + 12 + eh), s7 = __shfl(c, e + 14 + eh);
            __half2 h0 = *reinterpret_cast<const __half2*>(&Af[(size_t)s0 * 64]);
            __half2 h1 = *reinterpret_cast<const __half2*>(&Af[(size_t)s1 * 64]);
            __half2 h2 = *reinterpret_cast<const __half2*>(&Af[(size_t)s2 * 64]);
            __half2 h3 = *reinterpret_cast<const __half2*>(&Af[(size_t)s3 * 64]);
            __half2 h4 = *reinterpret_cast<const __half2*>(&Af[(size_t)s4 * 64]);
            __half2 h5 = *reinterpret_cast<const __half2*>(&Af[(size_t)s5 * 64]);
            __half2 h6 = *reinterpret_cast<const __half2*>(&Af[(size_t)s6 * 64]);
            __half2 h7 = *reinterpret_cast<const __half2*>(&Af[(size_t)s7 * 64]);
            float2 v0 = __half22float2(h0), v1 = __half22float2(h1);
            float2 v2 = __half22float2(h2), v3 = __half22float2(h3);
            float2 v4 = __half22float2(h4), v5 = __half22float2(h5);
            float2 v6 = __half22float2(h6), v7 = __half22float2(h7);
            acc.x += ((v0.x + v1.x) + (v2.x + v3.x)) + ((v4.x + v5.x) + (v6.x + v7.x));
            acc.y += ((v0.y + v1.y) + (v2.y + v3.y)) + ((v4.y + v5.y) + (v6.y + v7.y));
        }
        for (; e + 2 <= m; e += 2) {
            int s = __shfl(c, e + eh);
            float2 v = __half22float2(*reinterpret_cast<const __half2*>(&Af[(size_t)s * 64]));
            acc.x += v.x; acc.y += v.y;
        }
        if (e < m) {
            int s = __shfl(c, e);
            if (eh == 0) {
                float2 v = __half22float2(*reinterpret_cast<const __half2*>(&Af[(size_t)s * 64]));
                acc.x += v.x; acc.y += v.y;
            }
        }
    }
    acc.x += __shfl_xor(acc.x, 32);
    acc.y += __shfl_xor(acc.y, 32);
    float2 sv = __half22float2(*reinterpret_cast<const __half2*>(&Af[(size_t)d * 64]));
    acc.x += sv.x; acc.y += sv.y;
    return acc;
}

// pack 4 floats -> 4 halves (8B store)
__device__ __forceinline__ void store_h4(__half* dst, float a, float b, float c, float d) {
    __half2 p0 = __floats2half2_rn(a, b);
    __half2 p1 = __floats2half2_rn(c, d);
    uint2 pk;
    pk.x = *reinterpret_cast<unsigned*>(&p0);
    pk.y = *reinterpret_cast<unsigned*>(&p1);
    *reinterpret_cast<uint2*>(dst) = pk;
}

// ---- standalone register-blocked MM (layer 1): Yh = fp16(dis[row] * (X @ W1)) ----
template<int K>
__global__ __launch_bounds__(256) void mm_tiled(const float* __restrict__ X,
        const float* __restrict__ W, const float* __restrict__ dis,
        __half* __restrict__ Y, int n) {
    constexpr int KC = 64;
    __shared__ float xs[32][KC + 1];
    const int tid = threadIdx.x;
    const int j4 = tid & 15;
    const int rp = tid >> 4;
    const int row0 = blockIdx.x * 32;
    const int col0 = j4 * 4;
    float acc[2][4] = {};

    for (int kc = 0; kc < K; kc += KC) {
        __syncthreads();
        #pragma unroll
        for (int it = 0; it < 2; ++it) {
            int idx = it * 256 + tid;
            int r = idx >> 4, c4 = idx & 15;
            int row = row0 + r;
            float4 v = make_float4(0.f, 0.f, 0.f, 0.f);
            if (row < n) v = *reinterpret_cast<const float4*>(&X[(size_t)row * K + kc + c4 * 4]);
            xs[r][c4 * 4 + 0] = v.x; xs[r][c4 * 4 + 1] = v.y;
            xs[r][c4 * 4 + 2] = v.z; xs[r][c4 * 4 + 3] = v.w;
        }
        __syncthreads();
        #pragma unroll 16
        for (int k = 0; k < KC; ++k) {
            const float4 w = *reinterpret_cast<const float4*>(&W[(size_t)(kc + k) * 64 + col0]);
            const float x0 = xs[rp * 2 + 0][k];
            const float x1 = xs[rp * 2 + 1][k];
            acc[0][0] = fmaf(x0, w.x, acc[0][0]);
            acc[0][1] = fmaf(x0, w.y, acc[0][1]);
            acc[0][2] = fmaf(x0, w.z, acc[0][2]);
            acc[0][3] = fmaf(x0, w.w, acc[0][3]);
            acc[1][0] = fmaf(x1, w.x, acc[1][0]);
            acc[1][1] = fmaf(x1, w.y, acc[1][1]);
            acc[1][2] = fmaf(x1, w.z, acc[1][2]);
            acc[1][3] = fmaf(x1, w.w, acc[1][3]);
        }
    }
    #pragma unroll
    for (int r = 0; r < 2; ++r) {
        int row = row0 + rp * 2 + r;
        if (row < n) {
            float s = dis[row];
            store_h4(&Y[(size_t)row * 64 + col0],
                     acc[r][0] * s, acc[r][1] * s, acc[r][2] * s, acc[r][3] * s);
        }
    }
}

// ---- fused agg + MM, 32-row tile: xs = relu(dis*(agg+self)+b); Yh = fp16(dis*(xs@W)) ----
__global__ __launch_bounds__(256) void agg_mm_kernel(const __half* __restrict__ A,
        const int* __restrict__ rowptr, const int* __restrict__ col,
        const float* __restrict__ dis, const float* __restrict__ bagg,
        const float* __restrict__ W, __half* __restrict__ Y, int n) {
    __shared__ float xs[32][66];
    __shared__ float dl[32];
    const int tid = threadIdx.x;
    const int w = tid >> 6, lane = tid & 63;
    const int eh = lane >> 5, f2 = lane & 31;
    const int row0 = blockIdx.x * 32;
    const float2 bv = *reinterpret_cast<const float2*>(&bagg[2 * f2]);

    #pragma unroll
    for (int rr = 0; rr < 8; ++rr) {
        int lr = w * 8 + rr;
        int d = row0 + lr;
        if (d < n) {
            float2 acc = agg_row_h2(A, rowptr, col, d, eh, f2, lane);
            float dd = dis[d];
            if (eh == 0) {
                float2 o;
                o.x = fmaxf(dd * acc.x + bv.x, 0.0f);
                o.y = fmaxf(dd * acc.y + bv.y, 0.0f);
                *reinterpret_cast<float2*>(&xs[lr][2 * f2]) = o;
            }
            if (lane == 0) dl[lr] = dd;
        } else {
            if (eh == 0)
                *reinterpret_cast<float2*>(&xs[lr][2 * f2]) = make_float2(0.f, 0.f);
            if (lane == 0) dl[lr] = 0.0f;
        }
    }
    __syncthreads();

    const int j4 = tid & 15;
    const int rp = tid >> 4;
    const int col0 = j4 * 4;
    float acc[2][4] = {};
    #pragma unroll 16
    for (int k = 0; k < 64; ++k) {
        const float4 wv = *reinterpret_cast<const float4*>(&W[(size_t)k * 64 + col0]);
        const float x0 = xs[rp * 2 + 0][k];
        const float x1 = xs[rp * 2 + 1][k];
        acc[0][0] = fmaf(x0, wv.x, acc[0][0]);
        acc[0][1] = fmaf(x0, wv.y, acc[0][1]);
        acc[0][2] = fmaf(x0, wv.z, acc[0][2]);
        acc[0][3] = fmaf(x0, wv.w, acc[0][3]);
        acc[1][0] = fmaf(x1, wv.x, acc[1][0]);
        acc[1][1] = fmaf(x1, wv.y, acc[1][1]);
        acc[1][2] = fmaf(x1, wv.z, acc[1][2]);
        acc[1][3] = fmaf(x1, wv.w, acc[1][3]);
    }
    #pragma unroll
    for (int r = 0; r < 2; ++r) {
        int row = row0 + rp * 2 + r;
        if (row < n) {
            float s = dl[rp * 2 + r];
            store_h4(&Y[(size_t)row * 64 + col0],
                     acc[r][0] * s, acc[r][1] * s, acc[r][2] * s, acc[r][3] * s);
        }
    }
}

// ---- fused agg + FFN head (fp32 output) ----
__global__ __launch_bounds__(256) void agg_ffn_kernel(const __half* __restrict__ A,
        const int* __restrict__ rowptr, const int* __restrict__ col,
        const float* __restrict__ dis, const float* __restrict__ bagg,
        const float* __restrict__ Wf1, const float* __restrict__ bf1,
        const float* __restrict__ Wf2, const float* __restrict__ bf2,
        float* __restrict__ out, int n) {
    __shared__ float xs[32][66];
    __shared__ float h1[32][65];
    const int tid = threadIdx.x;
    const int w = tid >> 6, lane = tid & 63;
    const int eh = lane >> 5, f2 = lane & 31;
    const int row0 = blockIdx.x * 32;
    const float2 bv = *reinterpret_cast<const float2*>(&bagg[2 * f2]);

    #pragma unroll
    for (int rr = 0; rr < 8; ++rr) {
        int lr = w * 8 + rr;
        int d = row0 + lr;
        if (d < n) {
            float2 acc = agg_row_h2(A, rowptr, col, d, eh, f2, lane);
            float dd = dis[d];
            if (eh == 0) {
                float2 o;
                o.x = fmaxf(dd * acc.x + bv.x, 0.0f);
                o.y = fmaxf(dd * acc.y + bv.y, 0.0f);
                *reinterpret_cast<float2*>(&xs[lr][2 * f2]) = o;
            }
        } else {
            if (eh == 0)
                *reinterpret_cast<float2*>(&xs[lr][2 * f2]) = make_float2(0.f, 0.f);
        }
    }
    __syncthreads();

    const int j4 = tid & 15;
    const int rp = tid >> 4;
    const int col0 = j4 * 4;
    float acc[2][4] = {};
    #pragma unroll 16
    for (int k = 0; k < 64; ++k) {
        const float4 wv = *reinterpret_cast<const float4*>(&Wf1[(size_t)k * 64 + col0]);
        const float x0 = xs[rp * 2 + 0][k];
        const float x1 = xs[rp * 2 + 1][k];
        acc[0][0] = fmaf(x0, wv.x, acc[0][0]);
        acc[0][1] = fmaf(x0, wv.y, acc[0][1]);
        acc[0][2] = fmaf(x0, wv.z, acc[0][2]);
        acc[0][3] = fmaf(x0, wv.w, acc[0][3]);
        acc[1][0] = fmaf(x1, wv.x, acc[1][0]);
        acc[1][1] = fmaf(x1, wv.y, acc[1][1]);
        acc[1][2] = fmaf(x1, wv.z, acc[1][2]);
        acc[1][3] = fmaf(x1, wv.w, acc[1][3]);
    }
    #pragma unroll
    for (int c = 0; c < 4; ++c) {
        float b = bf1[col0 + c];
        h1[rp * 2 + 0][col0 + c] = fmaxf(acc[0][c] + b, 0.0f);
        h1[rp * 2 + 1][col0 + c] = fmaxf(acc[1][c] + b, 0.0f);
    }
    __syncthreads();

    const int lr = tid >> 3;
    const int cg = tid & 7;
    if (cg < 5) {
        float a0 = bf2[cg * 2 + 0], a1 = bf2[cg * 2 + 1];
        #pragma unroll 16
        for (int k = 0; k < 64; ++k) {
            float xv = h1[lr][k];
            a0 = fmaf(xv, Wf2[(size_t)k * 10 + cg * 2 + 0], a0);
            a1 = fmaf(xv, Wf2[(size_t)k * 10 + cg * 2 + 1], a1);
        }
        int row = row0 + lr;
        if (row < n) {
            out[(size_t)row * 10 + cg * 2 + 0] = a0;
            out[(size_t)row * 10 + cg * 2 + 1] = a1;
        }
    }
}

extern "C" void kernel_launch(void* const* d_in, const int* in_sizes, int n_in,
                              void* d_out, int out_size, void* d_ws, size_t ws_size,
                              hipStream_t stream) {
    const float* x   = (const float*)d_in[0];
    const int*   ei  = (const int*)d_in[1];
    const float* W1  = (const float*)d_in[2];
    const float* b1  = (const float*)d_in[3];
    const float* W2  = (const float*)d_in[4];
    const float* b2  = (const float*)d_in[5];
    const float* W3  = (const float*)d_in[6];
    const float* b3  = (const float*)d_in[7];
    const float* Wf1 = (const float*)d_in[8];
    const float* bf1 = (const float*)d_in[9];
    const float* Wf2 = (const float*)d_in[10];
    const float* bf2 = (const float*)d_in[11];
    float* out = (float*)d_out;

    const int N = N_NODES;
    const int E = in_sizes[1] / 2;
    const int* src = ei;
    const int* dst = ei + E;
    const int nblkE = (E + EPB - 1) / EPB;   // 782

    // workspace layout
    char* p = (char*)d_ws;
    int*    btot   = (int*)p;                p += (size_t)256 * 4;
    int*    bbase  = (int*)p;                p += (size_t)256 * 4;
    int*    rowptr = (int*)p;                p += (size_t)(50176 + 64) * 4;
    float*  dis    = (float*)p;              p += (size_t)50176 * 4;
    int*    col    = (int*)p;                p += (size_t)E * 4;
    int*    hist   = (int*)p;                p += (size_t)NBUCKET * nblkE * 4;
    unsigned* pairs = (unsigned*)p;          p += (size_t)E * 4;
    __half* A1     = (__half*)p;             p += (size_t)N * 64 * 2;
    __half* A2     = (__half*)p;

    // ---- CSR build: deterministic bucket counting sort (no global atomics) ----
    hist_kernel<<<nblkE, 256, 0, stream>>>(dst, E, hist, nblkE);
    colscan_kernel<<<NBUCKET, 256, 0, stream>>>(hist, nblkE, btot);
    btot_scan_kernel<<<1, 256, 0, stream>>>(btot, bbase);
    scatter_kernel<<<nblkE, 256, 0, stream>>>(src, dst, E, hist, bbase, nblkE, pairs);
    bucket_build_kernel<<<NBUCKET, 256, 0, stream>>>(pairs, btot, bbase, col, rowptr, dis, N);

    const int grid32 = (N + 31) / 32;      // 1563 blocks

    // A1 = fp16(dis * (x @ W1))
    mm_tiled<128><<<grid32, 256, 0, stream>>>(x, W1, dis, A1, N);
    // A2 = fp16(dis * (relu(dis*(agg(A1)+self)+b1) @ W2))
    agg_mm_kernel<<<grid32, 256, 0, stream>>>(A1, rowptr, col, dis, b1, W2, A2, N);
    // A1 = fp16(dis * (relu(dis*(agg(A2)+self)+b2) @ W3))
    agg_mm_kernel<<<grid32, 256, 0, stream>>>(A2, rowptr, col, dis, b2, W3, A1, N);
    // out = ffn(relu(dis*(agg(A1)+self)+b3))
    agg_ffn_kernel<<<grid32, 256, 0, stream>>>(A1, rowptr, col, dis, b3,
                                               Wf1, bf1, Wf2, bf2, out, N);
}